// Round 1
// baseline (198.719 us; speedup 1.0000x reference)
//
#include <hip/hip_runtime.h>
#include <math.h>

// Problem constants (match reference)
constexpr int B = 64, J = 8, K = 64, M = 32, D = 256;
constexpr int NNEG = K * M;            // 2048 negatives per batch
constexpr float TEMP = 0.1f;
constexpr float EPS = 1e-8f;
constexpr float SHIFT = 10.0f;         // 1/TEMP upper bound on |sim|

constexpr int SLICES = 8;                       // blocks per batch
constexpr int NEG_PER_BLOCK = NNEG / SLICES;    // 256 negs / block
constexpr int NBLK = B * SLICES;                // 512 blocks

// Kernel 1: per-(batch, slice) partial sum of exp(neg_sim - SHIFT) over
// label-matching negatives. Label is checked BEFORE reading the 1 KB neg
// vector -> only ~1/16 of the 128 MB negs array is ever fetched.
__global__ __launch_bounds__(256) void neg_partial_kernel(
    const float* __restrict__ childrens,
    const int*   __restrict__ gt_labels,
    const float* __restrict__ negs,
    const int*   __restrict__ neg_labels,
    float*       __restrict__ partials) {
  const int blk  = blockIdx.x;
  const int b    = blk / SLICES;
  const int s    = blk % SLICES;
  const int tid  = threadIdx.x;    // 0..255
  const int lane = tid & 63;
  const int wave = tid >> 6;       // 0..3

  __shared__ float child_hat[D];
  __shared__ float red[4];

  // ---- normalize child[b] (J index J-1) into LDS ----
  const float* child = childrens + ((size_t)b * J + (J - 1)) * D;
  float cv = child[tid];
  float ss = cv * cv;
  #pragma unroll
  for (int off = 32; off > 0; off >>= 1) ss += __shfl_down(ss, off, 64);
  if (lane == 0) red[wave] = ss;
  __syncthreads();
  const float norm2 = red[0] + red[1] + red[2] + red[3];
  const float inv_n = 1.0f / fmaxf(sqrtf(norm2), EPS);
  child_hat[tid] = cv * inv_n;
  __syncthreads();

  const int label = gt_labels[b * J + (J - 1)];

  // each wave handles 64 consecutive negs of this block's 256-neg slice
  const int neg_base = s * NEG_PER_BLOCK + wave * 64;
  const int*   nl      = neg_labels + (size_t)b * NNEG;
  const float* nv_base = negs + (size_t)b * NNEG * D;

  // child_hat fragment in registers: lane i holds elems [4i, 4i+4)
  const float4 ch = ((const float4*)child_hat)[lane];

  // coalesced label load + ballot -> wave-uniform list of matches
  const int nlab = nl[neg_base + lane];
  unsigned long long mask = __ballot(nlab == label);

  float acc = 0.0f;
  while (mask) {
    const int j = __ffsll((long long)mask) - 1;
    mask &= mask - 1;
    const float4* nv = (const float4*)(nv_base + (size_t)(neg_base + j) * D);
    const float4 x = nv[lane];                       // 16 B/lane, coalesced
    float dot = ch.x * x.x + ch.y * x.y + ch.z * x.z + ch.w * x.w;
    float nn  = x.x * x.x + x.y * x.y + x.z * x.z + x.w * x.w;
    #pragma unroll
    for (int off = 32; off > 0; off >>= 1) {
      dot += __shfl_down(dot, off, 64);
      nn  += __shfl_down(nn,  off, 64);
    }
    if (lane == 0) {
      const float sim = dot / (fmaxf(sqrtf(nn), EPS) * TEMP);
      acc += expf(sim - SHIFT);
    }
  }

  __syncthreads();              // red[] reuse
  if (lane == 0) red[wave] = acc;
  __syncthreads();
  if (tid == 0) partials[blk] = red[0] + red[1] + red[2] + red[3];
}

// Kernel 2: per-batch pos_sim + logsumexp finalize + global sum.
__global__ __launch_bounds__(256) void finalize_kernel(
    const float* __restrict__ childrens,
    const float* __restrict__ childrens_pos,
    const float* __restrict__ partials,
    float*       __restrict__ out) {
  const int tid  = threadIdx.x;
  const int lane = tid & 63;
  const int wave = tid >> 6;

  float wave_loss = 0.0f;
  for (int b = wave; b < B; b += 4) {
    const float4* child = (const float4*)(childrens     + ((size_t)b * J + (J - 1)) * D);
    const float4* pos   = (const float4*)(childrens_pos + ((size_t)b * J + (J - 1)) * D);
    const float4 c = child[lane];
    const float4 p = pos[lane];
    float cc = c.x * c.x + c.y * c.y + c.z * c.z + c.w * c.w;
    float pp = p.x * p.x + p.y * p.y + p.z * p.z + p.w * p.w;
    float cp = c.x * p.x + c.y * p.y + c.z * p.z + c.w * p.w;
    #pragma unroll
    for (int off = 32; off > 0; off >>= 1) {
      cc += __shfl_down(cc, off, 64);
      pp += __shfl_down(pp, off, 64);
      cp += __shfl_down(cp, off, 64);
    }
    if (lane == 0) {
      const float pos_sim =
          cp / (fmaxf(sqrtf(cc), EPS) * fmaxf(sqrtf(pp), EPS) * TEMP);
      float acc = expf(pos_sim - SHIFT);
      #pragma unroll
      for (int s = 0; s < SLICES; ++s) acc += partials[b * SLICES + s];
      wave_loss += logf(acc) + SHIFT - pos_sim;
    }
  }

  __shared__ float red[4];
  if (lane == 0) red[wave] = wave_loss;
  __syncthreads();
  if (tid == 0) out[0] = (red[0] + red[1] + red[2] + red[3]) / (2.0f * B);
}

extern "C" void kernel_launch(void* const* d_in, const int* in_sizes, int n_in,
                              void* d_out, int out_size, void* d_ws, size_t ws_size,
                              hipStream_t stream) {
  const float* childrens      = (const float*)d_in[0];   // (B,J,D)
  const float* childrens_pos  = (const float*)d_in[1];   // (B,J,D)
  const float* childrens_negs = (const float*)d_in[2];   // (B,K,M,D)
  const int*   gt_labels      = (const int*)d_in[3];     // (B,J)
  const int*   gt_label_negs  = (const int*)d_in[4];     // (B,K,M)
  float* out = (float*)d_out;

  float* partials = (float*)d_ws;   // NBLK floats

  neg_partial_kernel<<<NBLK, 256, 0, stream>>>(
      childrens, gt_labels, childrens_negs, gt_label_negs, partials);
  finalize_kernel<<<1, 256, 0, stream>>>(
      childrens, childrens_pos, partials, out);
}

// Round 2
// 178.018 us; speedup vs baseline: 1.1163x; 1.1163x over previous
//
#include <hip/hip_runtime.h>
#include <math.h>

// Problem constants (match reference)
constexpr int B = 64, J = 8, K = 64, M = 32, D = 256;
constexpr int NNEG = K * M;            // 2048 negatives per batch
constexpr float TEMP = 0.1f;
constexpr float EPS = 1e-8f;
constexpr float SHIFT = 10.0f;         // 1/TEMP upper bound on |sim|

constexpr int SLICES = 8;                       // blocks per batch
constexpr int NEG_PER_BLOCK = NNEG / SLICES;    // 256 negs / block
constexpr int NBLK = B * SLICES;                // 512 blocks

// Kernel 1: per-(batch, slice) partial sum of exp(neg_sim - SHIFT) over
// label-matching negatives. Labels checked BEFORE reading the 1 KB vectors
// -> only ~1/16 of the 128 MB negs array is fetched. Match loop processes
// up to 4 negs per round (4 independent loads in flight = MLP 4).
// Slice-0 blocks additionally compute pos_sim and fold exp(pos_sim-SHIFT)
// into their partial, so the finalize kernel is a single wave.
__global__ __launch_bounds__(256) void neg_partial_kernel(
    const float* __restrict__ childrens,
    const float* __restrict__ childrens_pos,
    const int*   __restrict__ gt_labels,
    const float* __restrict__ negs,
    const int*   __restrict__ neg_labels,
    float*       __restrict__ partials,
    float*       __restrict__ pos_sims) {
  const int blk  = blockIdx.x;
  const int b    = blk / SLICES;
  const int s    = blk % SLICES;
  const int tid  = threadIdx.x;    // 0..255
  const int lane = tid & 63;
  const int wave = tid >> 6;       // 0..3

  __shared__ float child_hat[D];
  __shared__ float red[4];
  __shared__ float redpp[4];
  __shared__ float redcp[4];

  // ---- normalize child[b] (J index J-1) into LDS ----
  const float* child = childrens + ((size_t)b * J + (J - 1)) * D;
  float cv = child[tid];
  float ss = cv * cv;
  #pragma unroll
  for (int off = 32; off > 0; off >>= 1) ss += __shfl_down(ss, off, 64);
  if (lane == 0) red[wave] = ss;
  __syncthreads();
  const float norm2 = red[0] + red[1] + red[2] + red[3];
  const float inv_n = 1.0f / fmaxf(sqrtf(norm2), EPS);
  child_hat[tid] = cv * inv_n;
  __syncthreads();

  const int label = gt_labels[b * J + (J - 1)];

  // each wave handles 64 consecutive negs of this block's 256-neg slice
  const int neg_base = s * NEG_PER_BLOCK + wave * 64;
  const int*   nl      = neg_labels + (size_t)b * NNEG;
  const float* nv_base = negs + (size_t)b * NNEG * D;

  // child_hat fragment in registers: lane i holds elems [4i, 4i+4)
  const float4 ch = ((const float4*)child_hat)[lane];

  // coalesced label load + ballot -> wave-uniform list of matches
  const int nlab = nl[neg_base + lane];
  unsigned long long mask = __ballot(nlab == label);

  float acc = 0.0f;
  while (mask) {
    // peel up to 4 set bits (wave-uniform); duplicates for t>=cnt are
    // cache-hit re-loads whose contribution is discarded
    int idx[4];
    int cnt = 0;
    idx[0] = __ffsll((long long)mask) - 1;
    mask &= mask - 1;
    cnt = 1;
    #pragma unroll
    for (int t = 1; t < 4; ++t) {
      if (mask) {
        idx[t] = __ffsll((long long)mask) - 1;
        mask &= mask - 1;
        ++cnt;
      } else {
        idx[t] = idx[0];
      }
    }

    float dot[4], nn[4];
    #pragma unroll
    for (int t = 0; t < 4; ++t) {
      const float4* nv =
          (const float4*)(nv_base + (size_t)(neg_base + idx[t]) * D);
      const float4 x = nv[lane];                   // 16 B/lane, coalesced
      dot[t] = ch.x * x.x + ch.y * x.y + ch.z * x.z + ch.w * x.w;
      nn[t]  = x.x * x.x + x.y * x.y + x.z * x.z + x.w * x.w;
    }
    #pragma unroll
    for (int off = 32; off > 0; off >>= 1) {
      #pragma unroll
      for (int t = 0; t < 4; ++t) {
        dot[t] += __shfl_down(dot[t], off, 64);
        nn[t]  += __shfl_down(nn[t],  off, 64);
      }
    }
    if (lane == 0) {
      #pragma unroll
      for (int t = 0; t < 4; ++t) {
        if (t < cnt) {
          const float sim = dot[t] / (fmaxf(sqrtf(nn[t]), EPS) * TEMP);
          acc += expf(sim - SHIFT);
        }
      }
    }
  }

  // ---- slice-0 blocks also compute pos_sim (block-uniform branch) ----
  if (s == 0) {
    const float* pos = childrens_pos + ((size_t)b * J + (J - 1)) * D;
    const float pv = pos[tid];
    float pp = pv * pv;
    float cp = child_hat[tid] * pv;
    #pragma unroll
    for (int off = 32; off > 0; off >>= 1) {
      pp += __shfl_down(pp, off, 64);
      cp += __shfl_down(cp, off, 64);
    }
    if (lane == 0) { redpp[wave] = pp; redcp[wave] = cp; }
  }

  if (lane == 0) red[wave] = acc;
  __syncthreads();
  if (tid == 0) {
    float total = red[0] + red[1] + red[2] + red[3];
    if (s == 0) {
      const float ppt = redpp[0] + redpp[1] + redpp[2] + redpp[3];
      const float cpt = redcp[0] + redcp[1] + redcp[2] + redcp[3];
      // child_hat already normalized -> cos = cp / max(|pos|,eps)
      const float pos_sim = cpt / (fmaxf(sqrtf(ppt), EPS) * TEMP);
      pos_sims[b] = pos_sim;
      total += expf(pos_sim - SHIFT);
    }
    partials[blk] = total;
  }
}

// Kernel 2: one wave; lane b finalizes batch b, shuffle-tree global sum.
__global__ __launch_bounds__(64) void finalize_kernel(
    const float* __restrict__ partials,
    const float* __restrict__ pos_sims,
    float*       __restrict__ out) {
  const int lane = threadIdx.x;   // 0..63 == batch index
  float sum = 0.0f;
  #pragma unroll
  for (int t = 0; t < SLICES; ++t) sum += partials[lane * SLICES + t];
  const float ps = pos_sims[lane];
  float loss = logf(sum) + SHIFT - ps;
  #pragma unroll
  for (int off = 32; off > 0; off >>= 1) loss += __shfl_down(loss, off, 64);
  if (lane == 0) out[0] = loss / (2.0f * B);
}

extern "C" void kernel_launch(void* const* d_in, const int* in_sizes, int n_in,
                              void* d_out, int out_size, void* d_ws, size_t ws_size,
                              hipStream_t stream) {
  const float* childrens      = (const float*)d_in[0];   // (B,J,D)
  const float* childrens_pos  = (const float*)d_in[1];   // (B,J,D)
  const float* childrens_negs = (const float*)d_in[2];   // (B,K,M,D)
  const int*   gt_labels      = (const int*)d_in[3];     // (B,J)
  const int*   gt_label_negs  = (const int*)d_in[4];     // (B,K,M)
  float* out = (float*)d_out;

  float* partials = (float*)d_ws;          // NBLK floats
  float* pos_sims = partials + NBLK;       // B floats

  neg_partial_kernel<<<NBLK, 256, 0, stream>>>(
      childrens, childrens_pos, gt_labels, childrens_negs, gt_label_negs,
      partials, pos_sims);
  finalize_kernel<<<1, 64, 0, stream>>>(partials, pos_sims, out);
}